// Round 3
// baseline (338.806 us; speedup 1.0000x reference)
//
#include <hip/hip_runtime.h>

constexpr int S    = 256;
constexpr int D    = 32;
constexpr int NH   = 4;
constexpr int DH   = 8;
constexpr int DFF  = 64;
constexpr int NL   = 4;
constexpr int IND  = 58;
constexpr int HOUT = 25;
constexpr int TPB  = 512;  // 1 window/block, 8 waves; 2 blocks/CU -> 4 waves/SIMD

typedef float  f2 __attribute__((ext_vector_type(2)));
typedef float  f4 __attribute__((ext_vector_type(4)));
typedef __fp16 h2 __attribute__((ext_vector_type(2)));
typedef __fp16 h4 __attribute__((ext_vector_type(4)));

__device__ __forceinline__ f4 MFMA16(h4 a, h4 b, f4 c) {
  return __builtin_amdgcn_mfma_f32_16x16x16f16(a, b, c, 0, 0, 0);
}

// LDS map (bytes), 64 KB. Liveness per layer:
//  HOFF: h f16 (ph1 A-src) -> attn O (ph2 out, GEMM2 A-src) -> h' f16 (G34 A-src)
//  QKOFF: Q|K (ph2 in)   [t eliminated: GEMM3->GEMM4 fused in registers]
//  VOFF: V^T (ph2 in) -> O' f16 (LN1 in) -> O'' f16 (LN2 in)
constexpr int HOFF  = 0;      // 16 KB  [256][32] f16, 8B chunks ^(tok&7)
constexpr int QKOFF = 16384;  // 32 KB
constexpr int VOFF  = 49152;  // 16 KB

__device__ __forceinline__ unsigned pk2(float a, float b) {
  h2 h = __builtin_amdgcn_cvt_pkrtz(a, b);
  return __builtin_bit_cast(unsigned, h);
}

__device__ __forceinline__ float exp2fast(float x) {
#if __has_builtin(__builtin_amdgcn_exp2f)
  return __builtin_amdgcn_exp2f(x);   // v_exp_f32 = 2^x, one trans op
#else
  return exp2f(x);
#endif
}

// Compile-time + in-wave-order fence for same-wave LDS RAW.
__device__ __forceinline__ void wave_fence() {
  __builtin_amdgcn_wave_barrier();
  __builtin_amdgcn_sched_barrier(0);
}

// packed-fp32 dot. All register-array loops must FULLY unroll (r3 lesson).
template<int NF2>
__device__ __forceinline__ float dotp(const float* __restrict__ w,
                                      const float* __restrict__ v) {
  const f2* W = (const f2*)w;
  const f2* V = (const f2*)v;
  f2 a0 = {0.f, 0.f}, a1 = {0.f, 0.f};
#pragma unroll
  for (int i = 0; i < NF2; i += 2) a0 += V[i] * W[i];
#pragma unroll
  for (int i = 1; i < NF2; i += 2) a1 += V[i] * W[i];
  f2 s = a0 + a1;
  return s.x + s.y;
}

// tanh-approx GELU via exp2 (log2e folded; verified family r7-r10)
__device__ __forceinline__ float gelu(float x) {
  float u = 2.3022082f * fmaf(0.044715f * x * x, x, x);  // 1.59576912*log2(e)
  return x * __builtin_amdgcn_rcpf(1.0f + exp2fast(-u));
}

// LayerNorm over a 32-feature token split across partner lanes (tid^1).
// h = this thread's 16 features; g16/b16 pre-offset by half*16.
__device__ __forceinline__ void lnorm_half(float* h, const float* __restrict__ g16,
                                           const float* __restrict__ b16) {
  f2* hv = (f2*)h;
  f2 s0 = hv[0], s1 = hv[1];
#pragma unroll
  for (int i = 2; i < 8; i += 2) { s0 += hv[i]; s1 += hv[i + 1]; }
  f2 sv = s0 + s1;
  float s = sv.x + sv.y;
  s += __shfl_xor(s, 1);                       // partner lane: other 16 feats
  const float m = s * (1.0f / D);
  const f2 m2 = {m, m};
  f2 v0 = {0.f, 0.f}, v1 = {0.f, 0.f};
#pragma unroll
  for (int i = 0; i < 8; i += 2) {
    f2 c0 = hv[i] - m2;     v0 += c0 * c0;
    f2 c1 = hv[i + 1] - m2; v1 += c1 * c1;
  }
  f2 vv = v0 + v1;
  float v = vv.x + vv.y;
  v += __shfl_xor(v, 1);
  const float inv = __builtin_amdgcn_rsqf(v * (1.0f / D) + 1e-5f);
  const f2 inv2 = {inv, inv};
  const f2 mi2 = {-m * inv, -m * inv};
  const f2* g2 = (const f2*)g16;
  const f2* b2 = (const f2*)b16;
#pragma unroll
  for (int i = 0; i < 8; ++i) {
    f2 t = hv[i] * inv2 + mi2;
    hv[i] = t * g2[i] + b2[i];
  }
}

// Embed 16 features (half*16..+16) of one token.
__device__ __forceinline__ void embed_half(
    const float* __restrict__ xrow, int lay, int half,
    const float* __restrict__ fpw, const float* __restrict__ fpb,
    const float* __restrict__ lemb, const float* __restrict__ fB,
    float* __restrict__ h) {
  float xr[IND];
  const f2* xv = (const f2*)xrow;
#pragma unroll
  for (int i = 0; i < 29; ++i) { f2 t = xv[i]; xr[2 * i] = t.x; xr[2 * i + 1] = t.y; }
  const int fo = half * 16;
  const float* le = lemb + lay * D + fo;
  const float qsh = 0.25f * half;  // cos(2pi t) = sin(2pi(t+0.25))
  float pe[16];
#pragma unroll
  for (int k = 0; k < 16; ++k) {
    float t = xr[0] * fB[k] + xr[1] * fB[16 + k] + xr[2] * fB[32 + k];
#if __has_builtin(__builtin_amdgcn_sinf) && __has_builtin(__builtin_amdgcn_fractf)
    pe[k] = __builtin_amdgcn_sinf(__builtin_amdgcn_fractf(t + qsh));
#else
    float u = t + qsh;
    pe[k] = sinf(6.2831853071795864f * (u - floorf(u)));
#endif
  }
#pragma unroll
  for (int dd = 0; dd < 16; ++dd)
    h[dd] = dotp<29>(fpw + (fo + dd) * IND, xr) + fpb[fo + dd] + le[dd] + pe[dd];
}

// ---- shared fragment helpers (layouts verified r8/r11) ----
__device__ __forceinline__ h4 bfrag(const float* __restrict__ W, int row,
                                    int K, int kh, int quad) {
  f4 w = *(const f4*)(W + row * K + kh * 16 + quad * 4);
  uint2 p{pk2(w.x, w.y), pk2(w.z, w.w)};
  return __builtin_bit_cast(h4, p);
}
// token frag from [tok][32] f16, 8B chunks swizzled ^(tok&7)
__device__ __forceinline__ h4 afrag32(const unsigned char* sm, int base,
                                      int tok, int kh, int quad) {
  return *(const h4*)(sm + base + tok * 64 + (((kh * 4 + quad) ^ (tok & 7)) * 8));
}

// Write this thread's 16 features as half of a swizzled f16 row.
__device__ __forceinline__ void store_h16_half(unsigned char* sm, int tok,
                                               int half, const float* __restrict__ h) {
#pragma unroll
  for (int c = 0; c < 4; ++c) {
    uint2 p{pk2(h[4 * c], h[4 * c + 1]), pk2(h[4 * c + 2], h[4 * c + 3])};
    *(uint2*)(sm + HOFF + tok * 64 + (((half * 4 + c) ^ (tok & 7)) * 8)) = p;
  }
}
// Accumulate half of a swizzled [tok][32] row into h (residual add).
__device__ __forceinline__ void add_row_half(const unsigned char* sm, int base,
                                             int tok, int half, float* __restrict__ h) {
  f2* hv = (f2*)h;
#pragma unroll
  for (int c = 0; c < 4; ++c) {
    h4 q = *(const h4*)(sm + base + tok * 64 + (((half * 4 + c) ^ (tok & 7)) * 8));
    f2 lo = {(float)q[0], (float)q[1]};
    f2 hi = {(float)q[2], (float)q[3]};
    hv[2 * c] += lo;
    hv[2 * c + 1] += hi;
  }
}

// (512,4): 4 waves/EU -> 2 blocks/CU, VGPR cap 128. Per-thread state is
// halved vs the 256-thread variant (h[16], half tile counts) to fit.
__global__ void __launch_bounds__(TPB, 4)
spai_fused(const float* __restrict__ x,    const int*   __restrict__ layers,
           const float* __restrict__ fpw,  const float* __restrict__ fpb,
           const float* __restrict__ lemb, const float* __restrict__ fB,
           const float* __restrict__ ipw,  const float* __restrict__ ipb,
           const float* __restrict__ opw,  const float* __restrict__ opb,
           const float* __restrict__ ln1g, const float* __restrict__ ln1b,
           const float* __restrict__ w1,   const float* __restrict__ b1,
           const float* __restrict__ w2,   const float* __restrict__ b2,
           const float* __restrict__ ln2g, const float* __restrict__ ln2b,
           const float* __restrict__ nog,  const float* __restrict__ nob,
           const float* __restrict__ hw,   const float* __restrict__ hb,
           float* __restrict__ out) {
  __shared__ __align__(16) unsigned char sm[65536];
  const int tid   = threadIdx.x;
  const int lane  = tid & 63;
  const int wave  = tid >> 6;    // 0..7; owns tokens [32*wave, 32*wave+32)
  const int n16   = lane & 15;
  const int quad  = lane >> 4;
  const int qs    = quad & 1;
  const int token = tid >> 1;    // 0..255
  const int half  = tid & 1;     // feature half of the token
  const size_t blk_tok = (size_t)blockIdx.x * S;

  float h[16];                   // features [half*16, half*16+16) of token
  embed_half(x + (blk_tok + token) * IND, layers[blk_tok + token], half,
             fpw, fpb, lemb, fB, h);
  store_h16_half(sm, token, half, h);
  wave_fence();

  for (int l = 0; l < NL; ++l) {
    // Barrier 1/3: ph1's V^T (and Q|K) writes scatter into rows whose prior
    // contents (O''/residual) other waves read; also publishes embed h (l=0).
    __syncthreads();

    const float* Wi = ipw + l * (3 * D) * D;
    const float* Bi = ipb + l * (3 * D);

    // ---- ph1: QKV GEMM; wave owns token tiles {2w, 2w+1} ------------------
    // Q|K transposed (weights as A-op); bias in C-init; Q pre-scaled by
    // (1/sqrt(dh))*log2(e) so ph2 uses raw v_exp_f32.
    {
      h4 Bf[12]; f4 bqk[4]; float bv[2];
#pragma unroll
      for (int nt = 0; nt < 6; ++nt) {
        const float sc = (nt < 2) ? 0.51006973f : 1.0f;  // 0.35355339*log2(e)
#pragma unroll
        for (int kh = 0; kh < 2; ++kh) {
          f4 wv = *(const f4*)(Wi + (nt * 16 + n16) * D + kh * 16 + quad * 4) * sc;
          uint2 wp{pk2(wv.x, wv.y), pk2(wv.z, wv.w)};
          Bf[nt * 2 + kh] = __builtin_bit_cast(h4, wp);
        }
        if (nt < 4)
          bqk[nt] = *(const f4*)(Bi + nt * 16 + quad * 4) * sc;
        else
          bv[nt - 4] = Bi[nt * 16 + n16];
      }
      h4 Ah[4];
#pragma unroll
      for (int ii = 0; ii < 2; ++ii) {
        const int tok = (wave * 2 + ii) * 16 + n16;
        Ah[ii * 2]     = afrag32(sm, HOFF, tok, 0, quad);
        Ah[ii * 2 + 1] = afrag32(sm, HOFF, tok, 1, quad);
      }
      const int kswz = n16 & 7;  // == tok&7 for tok = tile*16+n16
#pragma unroll
      for (int ii = 0; ii < 2; ++ii) {
        const int tok = (wave * 2 + ii) * 16 + n16;
#pragma unroll
        for (int nt = 0; nt < 4; ++nt) {  // Q|K: C^T[feat][tok]
          f4 C = bqk[nt];
          C = MFMA16(Bf[nt * 2], Ah[ii * 2], C);
          C = MFMA16(Bf[nt * 2 + 1], Ah[ii * 2 + 1], C);
          uint2 p{pk2(C[0], C[1]), pk2(C[2], C[3])};
          *(uint2*)(sm + QKOFF + tok * 128 +
                    (((nt * 2 + (quad >> 1)) ^ kswz) * 16) + (quad & 1) * 8) = p;
        }
#pragma unroll
        for (int nt = 4; nt < 6; ++nt) {  // V token-major -> V^T
          const float bb = bv[nt - 4];
          f4 C = {bb, bb, bb, bb};
          C = MFMA16(Ah[ii * 2], Bf[nt * 2], C);
          C = MFMA16(Ah[ii * 2 + 1], Bf[nt * 2 + 1], C);
          uint2 p{pk2(C[0], C[1]), pk2(C[2], C[3])};
          const int vf = (nt - 4) * 16 + n16;
          const int tc = (wave * 2 + ii) * 4 + quad;  // tok>>2
          *(uint2*)(sm + VOFF + vf * 512 + ((tc ^ ((vf & 7) << 1)) * 8)) = p;
        }
      }
    }
    // Barrier 2/3: Q|K|V visible to all waves for ph2.
    __syncthreads();

    // ---- ph2: flash attention; head = wave>>1, it-range split by wave&1 ---
    // O^T = mfma(V^T, P); A-row 8 = ones so MFMA also produces lsum.
    {
      const int hh  = wave >> 1;
      const int sub = wave & 1;
      const int m   = n16;
      const int msw = m & 7;
      h4 Kf[16], Vf[16];
      const int kbase = QKOFF + (((4 + hh) ^ msw) * 16) + qs * 8;
#pragma unroll
      for (int jt = 0; jt < 16; ++jt) {
        uint2 a = *(const uint2*)(sm + kbase + (jt * 16 + m) * 128);
        if (quad >= 2) { a.x = 0u; a.y = 0u; }   // dh 8->16 zero pad (k dim)
        Kf[jt] = __builtin_bit_cast(h4, a);
      }
      const unsigned fill = (m == 8) ? 0x3C003C00u : 0u;  // row 8 = ones
      const int vbase = VOFF + (hh * 8 + msw) * 512;
      const int vkey  = msw << 1;
#pragma unroll
      for (int jt = 0; jt < 16; ++jt) {
        uint2 a = *(const uint2*)(sm + vbase + (((jt * 4 + quad) ^ vkey) * 8));
        if (m >= 8) { a.x = fill; a.y = fill; }  // rows 9..15 zero, row 8 ones
        Vf[jt] = __builtin_bit_cast(h4, a);
      }
      const int qoff = QKOFF + ((hh ^ msw) * 16) + qs * 8;
      const int ooff = HOFF + (((hh * 2 + quad) ^ msw) * 8);  // quad<2 valid

#pragma unroll 2
      for (int i2 = 0; i2 < 8; ++i2) {
        const int it = sub * 8 + i2;
        const int ti = it * 16 + m;
        h4 Qf = *(const h4*)(sm + qoff + ti * 128);
        f4 Of0 = {0.f, 0.f, 0.f, 0.f}, Of1 = {0.f, 0.f, 0.f, 0.f};
        const f4 Z = {0.f, 0.f, 0.f, 0.f};
#pragma unroll
        for (int jt = 0; jt < 16; ++jt) {
          f4 T = MFMA16(Kf[jt], Qf, Z);
          uint2 pu{pk2(exp2fast(T[0]), exp2fast(T[1])),
                   pk2(exp2fast(T[2]), exp2fast(T[3]))};
          h4 P = __builtin_bit_cast(h4, pu);  // C-frag of T == B-frag of P
          if (jt & 1) Of1 = MFMA16(Vf[jt], P, Of1);
          else        Of0 = MFMA16(Vf[jt], P, Of0);
        }
        f4 Of = Of0 + Of1;
        // C row 8 (quad==2, elem 0) = softmax denominator
        float rinv = __builtin_amdgcn_rcpf(Of[0]);
        rinv = __builtin_bit_cast(
            float, __builtin_amdgcn_ds_bpermute(
                       (32 + m) << 2, __builtin_bit_cast(int, rinv)));
        if (quad < 2) {  // rows 0..7 = O features hh*8+quad*4+r of token ti
          f4 o = Of * rinv;
          uint2 p{pk2(o[0], o[1]), pk2(o[2], o[3])};
          *(uint2*)(sm + ooff + ti * 64) = p;
        }
      }
    }
    // Barrier 3/3: O (cross-head) visible; all K/V reads done.
    __syncthreads();

    // ---- GEMM2: O'^T = Wo x O^T -> VOFF (V dead); own-wave tokens ---------
    {
      const float* Wo = opw + l * D * D;
      const float* Bo = opb + l * D;
      h4 Bf[4]; f4 bo[2];
#pragma unroll
      for (int nt = 0; nt < 2; ++nt) {
        bo[nt] = *(const f4*)(Bo + nt * 16 + quad * 4);
#pragma unroll
        for (int kh = 0; kh < 2; ++kh)
          Bf[nt * 2 + kh] = bfrag(Wo, nt * 16 + n16, 32, kh, quad);
      }
      const int kswz = n16 & 7;
#pragma unroll
      for (int ii = 0; ii < 2; ++ii) {
        const int tok = (wave * 2 + ii) * 16 + n16;
        h4 A0 = afrag32(sm, HOFF, tok, 0, quad);
        h4 A1 = afrag32(sm, HOFF, tok, 1, quad);
#pragma unroll
        for (int nt = 0; nt < 2; ++nt) {
          f4 C = bo[nt];
          C = MFMA16(Bf[nt * 2], A0, C);
          C = MFMA16(Bf[nt * 2 + 1], A1, C);
          uint2 p{pk2(C[0], C[1]), pk2(C[2], C[3])};
          *(uint2*)(sm + VOFF + tok * 64 + (((nt * 4 + quad) ^ kswz) * 8)) = p;
        }
      }
    }
    wave_fence();  // O' rows are own-wave

    // ---- token: h += O'; LN1; h' f16 -> HOFF (own rows) -------------------
    add_row_half(sm, VOFF, token, half, h);
    lnorm_half(h, ln1g + l * D + half * 16, ln1b + l * D + half * 16);
    store_h16_half(sm, token, half, h);
    wave_fence();

    // ---- fused GEMM3+GEMM4 (t stays in registers): ------------------------
    // t^T = gelu(Wa x h'^T); GEMM3's C-frag (after gelu) IS GEMM4's B-frag
    // at kh=ft (lane n16 = token col, quad*4+e = k within ft block).
    {
      const float* Wa = w1 + l * DFF * D;
      const float* Ba = b1 + l * DFF;
      const float* Wb = w2 + l * D * DFF;
      const float* Bb = b2 + l * D;
      h4 WaF[8]; f4 ba[4]; h4 WbF[8]; f4 bb[2];
#pragma unroll
      for (int ft = 0; ft < 4; ++ft) {
        ba[ft] = *(const f4*)(Ba + ft * 16 + quad * 4);
#pragma unroll
        for (int kh = 0; kh < 2; ++kh)
          WaF[ft * 2 + kh] = bfrag(Wa, ft * 16 + n16, 32, kh, quad);
      }
#pragma unroll
      for (int nt = 0; nt < 2; ++nt) {
        bb[nt] = *(const f4*)(Bb + nt * 16 + quad * 4);
#pragma unroll
        for (int kh = 0; kh < 4; ++kh)
          WbF[nt * 4 + kh] = bfrag(Wb, nt * 16 + n16, 64, kh, quad);
      }
      const int kswz = n16 & 7;
#pragma unroll
      for (int tt = 0; tt < 2; ++tt) {
        const int tok = (wave * 2 + tt) * 16 + n16;
        h4 A0 = afrag32(sm, HOFF, tok, 0, quad);
        h4 A1 = afrag32(sm, HOFF, tok, 1, quad);
        h4 Pf[4];
#pragma unroll
        for (int ft = 0; ft < 4; ++ft) {
          f4 C = ba[ft];
          C = MFMA16(WaF[ft * 2], A0, C);
          C = MFMA16(WaF[ft * 2 + 1], A1, C);
          uint2 p{pk2(gelu(C[0]), gelu(C[1])), pk2(gelu(C[2]), gelu(C[3]))};
          Pf[ft] = __builtin_bit_cast(h4, p);
        }
#pragma unroll
        for (int nt = 0; nt < 2; ++nt) {
          f4 C = bb[nt];
#pragma unroll
          for (int ft = 0; ft < 4; ++ft) C = MFMA16(WbF[nt * 4 + ft], Pf[ft], C);
          uint2 p{pk2(C[0], C[1]), pk2(C[2], C[3])};
          *(uint2*)(sm + VOFF + tok * 64 + (((nt * 4 + quad) ^ kswz) * 8)) = p;
        }
      }
    }
    wave_fence();  // O'' rows are own-wave

    // ---- token: h += O''; LN2; h f16 -> HOFF (next layer's ph1 src) -------
    add_row_half(sm, VOFF, token, half, h);
    lnorm_half(h, ln2g + l * D + half * 16, ln2b + l * D + half * 16);
    if (l < NL - 1) store_h16_half(sm, token, half, h);
    wave_fence();
  }

  // ---------- final LN + head ----------
  __syncthreads();  // staging overlays HOFF+QKOFF still read by other waves
  lnorm_half(h, nog + half * 16, nob + half * 16);
  float* hs = (float*)sm;  // 25.6 KB staging
#pragma unroll
  for (int o = 0; o < HOUT; ++o) {
    float p = dotp<8>(hw + o * D + half * 16, h);
    p += __shfl_xor(p, 1);                    // partner's half of the dot
    if ((o < 13) == (half == 0)) hs[token * HOUT + o] = p + hb[o];
  }
  __syncthreads();
  f2* og = (f2*)(out + blk_tok * HOUT);
  const f2* os2 = (const f2*)hs;
  for (int i = tid; i < S * HOUT / 2; i += TPB) og[i] = os2[i];
}

extern "C" void kernel_launch(void* const* d_in, const int* in_sizes, int n_in,
                              void* d_out, int out_size, void* d_ws, size_t ws_size,
                              hipStream_t stream) {
  const float* x    = (const float*)d_in[0];
  const int*   lays = (const int*)  d_in[1];
  const float* fpw  = (const float*)d_in[2];
  const float* fpb  = (const float*)d_in[3];
  const float* lemb = (const float*)d_in[4];
  const float* fB   = (const float*)d_in[5];
  const float* ipw  = (const float*)d_in[6];
  const float* ipb  = (const float*)d_in[7];
  const float* opw  = (const float*)d_in[8];
  const float* opb  = (const float*)d_in[9];
  const float* ln1g = (const float*)d_in[10];
  const float* ln1b = (const float*)d_in[11];
  const float* w1   = (const float*)d_in[12];
  const float* b1   = (const float*)d_in[13];
  const float* w2   = (const float*)d_in[14];
  const float* b2   = (const float*)d_in[15];
  const float* ln2g = (const float*)d_in[16];
  const float* ln2b = (const float*)d_in[17];
  const float* nog  = (const float*)d_in[18];
  const float* nob  = (const float*)d_in[19];
  const float* hw   = (const float*)d_in[20];
  const float* hb   = (const float*)d_in[21];
  float* out = (float*)d_out;

  const int nwin = in_sizes[0] / (S * IND);  // 512 windows
  spai_fused<<<nwin, TPB, 0, stream>>>(x, lays, fpw, fpb, lemb, fB, ipw, ipb,
                                       opw, opb, ln1g, ln1b, w1, b1, w2, b2,
                                       ln2g, ln2b, nog, nob, hw, hb, out);
}

// Round 5
// 245.128 us; speedup vs baseline: 1.3822x; 1.3822x over previous
//
#include <hip/hip_runtime.h>

constexpr int S    = 256;
constexpr int D    = 32;
constexpr int NH   = 4;
constexpr int DH   = 8;
constexpr int DFF  = 64;
constexpr int NL   = 4;
constexpr int IND  = 58;
constexpr int HOUT = 25;
constexpr int TPB  = 256;  // 1 window/block, 4 waves; 2 blocks/CU (proven shell)
                           // 512-thread variants SPILL (re-confirmed round 3:
                           // VGPR=64, 60MB scratch, 148->249us). Do not retry.

typedef float  f2 __attribute__((ext_vector_type(2)));
typedef float  f4 __attribute__((ext_vector_type(4)));
typedef __fp16 h2 __attribute__((ext_vector_type(2)));
typedef __fp16 h4 __attribute__((ext_vector_type(4)));

__device__ __forceinline__ f4 MFMA16(h4 a, h4 b, f4 c) {
  return __builtin_amdgcn_mfma_f32_16x16x16f16(a, b, c, 0, 0, 0);
}

// LDS map (bytes), 64 KB. Liveness per layer:
//  HOFF: h f16 (ph1 A-src) -> attn O (ph2 out, GEMM2 src) -> h' f16 (G34 src)
//  QKOFF: Q|K (ph2 in)   [t eliminated: GEMM3->GEMM4 fused in registers]
//  VOFF: V^T (ph2 in) -> O' f16 (LN1 in) -> O'' f16 (LN2 in)
constexpr int HOFF  = 0;      // 16 KB  [256][32] f16, 8B chunks ^(tok&7)
constexpr int QKOFF = 16384;  // 32 KB
constexpr int VOFF  = 49152;  // 16 KB

__device__ __forceinline__ unsigned pk2(float a, float b) {
  h2 h = __builtin_amdgcn_cvt_pkrtz(a, b);
  return __builtin_bit_cast(unsigned, h);
}

__device__ __forceinline__ float exp2fast(float x) {
#if __has_builtin(__builtin_amdgcn_exp2f)
  return __builtin_amdgcn_exp2f(x);   // v_exp_f32 = 2^x, one trans op
#else
  return exp2f(x);
#endif
}

// Compile-time + in-wave-order fence for same-wave LDS RAW.
__device__ __forceinline__ void wave_fence() {
  __builtin_amdgcn_wave_barrier();
  __builtin_amdgcn_sched_barrier(0);
}

// packed-fp32 dot. All register-array loops must FULLY unroll (r3 lesson).
template<int NF2>
__device__ __forceinline__ float dotp(const float* __restrict__ w,
                                      const float* __restrict__ v) {
  const f2* W = (const f2*)w;
  const f2* V = (const f2*)v;
  f2 a0 = {0.f, 0.f}, a1 = {0.f, 0.f};
#pragma unroll
  for (int i = 0; i < NF2; i += 2) a0 += V[i] * W[i];
#pragma unroll
  for (int i = 1; i < NF2; i += 2) a1 += V[i] * W[i];
  f2 s = a0 + a1;
  return s.x + s.y;
}

// tanh-approx GELU via exp2 (log2e folded; verified family r7-r10)
__device__ __forceinline__ float gelu(float x) {
  float u = 2.3022082f * fmaf(0.044715f * x * x, x, x);  // 1.59576912*log2(e)
  return x * __builtin_amdgcn_rcpf(1.0f + exp2fast(-u));
}

// LayerNorm on 32 f32 regs, packed-f32 (v_pk_*) form.
__device__ __forceinline__ void lnorm(float* h, const float* __restrict__ g,
                                      const float* __restrict__ b) {
  f2* hv = (f2*)h;
  f2 s0 = hv[0], s1 = hv[1];
#pragma unroll
  for (int i = 2; i < 16; i += 2) { s0 += hv[i]; s1 += hv[i + 1]; }
  f2 s = s0 + s1;
  const float m = (s.x + s.y) * (1.0f / D);
  const f2 m2 = {m, m};
  f2 v0 = {0.f, 0.f}, v1 = {0.f, 0.f};
#pragma unroll
  for (int i = 0; i < 16; i += 2) {
    f2 c0 = hv[i] - m2;     v0 += c0 * c0;
    f2 c1 = hv[i + 1] - m2; v1 += c1 * c1;
  }
  f2 vs = v0 + v1;
  const float inv = __builtin_amdgcn_rsqf((vs.x + vs.y) * (1.0f / D) + 1e-5f);
  const f2 inv2 = {inv, inv};
  const f2 mi2 = {-m * inv, -m * inv};
  const f2* g2 = (const f2*)g;
  const f2* b2 = (const f2*)b;
#pragma unroll
  for (int i = 0; i < 16; ++i) {
    f2 t = hv[i] * inv2 + mi2;   // (h-m)*inv  as pk_fma
    hv[i] = t * g2[i] + b2[i];   // *g + b     as pk_fma
  }
}

__device__ __forceinline__ void embed_token(
    const float* __restrict__ xrow, int lay,
    const float* __restrict__ fpw, const float* __restrict__ fpb,
    const float* __restrict__ lemb, const float* __restrict__ fB,
    float* __restrict__ h) {
  float xr[IND];
  const f2* xv = (const f2*)xrow;
#pragma unroll
  for (int i = 0; i < 29; ++i) { f2 t = xv[i]; xr[2 * i] = t.x; xr[2 * i + 1] = t.y; }
  const float* le = lemb + lay * D;
  float pe[D];
#pragma unroll
  for (int k = 0; k < 16; ++k) {
    // sin(2*pi*t) = v_sin(fract(t)) in revolutions (verified r9/r10)
    float t = xr[0] * fB[k] + xr[1] * fB[16 + k] + xr[2] * fB[32 + k];
#if __has_builtin(__builtin_amdgcn_sinf) && __has_builtin(__builtin_amdgcn_cosf) && __has_builtin(__builtin_amdgcn_fractf)
    float u = __builtin_amdgcn_fractf(t);
    pe[k]      = __builtin_amdgcn_sinf(u);
    pe[16 + k] = __builtin_amdgcn_cosf(u);
#else
    float sv, cv;
    sincosf(6.2831853071795864f * (t - floorf(t)), &sv, &cv);
    pe[k] = sv; pe[16 + k] = cv;
#endif
  }
#pragma unroll
  for (int d = 0; d < D; ++d)
    h[d] = dotp<29>(fpw + d * IND, xr) + fpb[d] + le[d] + pe[d];
}

// ---- shared fragment helpers (layouts verified r8/r11) ----
// frag from f32 weight row-major [N][K]: lane n16 = row, kh = 16-wide k-half.
// Identical register format serves as A- or B-operand; MFMA operand order
// selects which (transposed output when used as A).
__device__ __forceinline__ h4 bfrag(const float* __restrict__ W, int row,
                                    int K, int kh, int quad) {
  f4 w = *(const f4*)(W + row * K + kh * 16 + quad * 4);
  uint2 p{pk2(w.x, w.y), pk2(w.z, w.w)};
  return __builtin_bit_cast(h4, p);
}
// token frag from [tok][32] f16, 8B chunks swizzled ^(tok&7)
__device__ __forceinline__ h4 afrag32(const unsigned char* sm, int base,
                                      int tok, int kh, int quad) {
  return *(const h4*)(sm + base + tok * 64 + (((kh * 4 + quad) ^ (tok & 7)) * 8));
}

// Write this thread's h (f32 regs) as swizzled f16 row into HOFF.
__device__ __forceinline__ void store_h16(unsigned char* sm, int tok,
                                          const float* __restrict__ h) {
#pragma unroll
  for (int c = 0; c < 8; ++c) {
    uint2 p{pk2(h[4 * c], h[4 * c + 1]), pk2(h[4 * c + 2], h[4 * c + 3])};
    *(uint2*)(sm + HOFF + tok * 64 + ((c ^ (tok & 7)) * 8)) = p;
  }
}
// Read a swizzled [tok][32] f16 row, accumulate into h (residual add).
__device__ __forceinline__ void add_row32(const unsigned char* sm, int base,
                                          int tok, float* __restrict__ h) {
  f2* hv = (f2*)h;
#pragma unroll
  for (int c = 0; c < 8; ++c) {
    h4 q = *(const h4*)(sm + base + tok * 64 + ((c ^ (tok & 7)) * 8));
    f2 lo = {(float)q[0], (float)q[1]};
    f2 hi = {(float)q[2], (float)q[3]};
    hv[2 * c] += lo;
    hv[2 * c + 1] += hi;
  }
}

// launch_bounds: ONLY (256,2) is spill-free for this family (measured r5-r10,
// re-confirmed round 3 on the 512-thread variant).
__global__ void __launch_bounds__(TPB, 2)
spai_fused(const float* __restrict__ x,    const int*   __restrict__ layers,
           const float* __restrict__ fpw,  const float* __restrict__ fpb,
           const float* __restrict__ lemb, const float* __restrict__ fB,
           const float* __restrict__ ipw,  const float* __restrict__ ipb,
           const float* __restrict__ opw,  const float* __restrict__ opb,
           const float* __restrict__ ln1g, const float* __restrict__ ln1b,
           const float* __restrict__ w1,   const float* __restrict__ b1,
           const float* __restrict__ w2,   const float* __restrict__ b2,
           const float* __restrict__ ln2g, const float* __restrict__ ln2b,
           const float* __restrict__ nog,  const float* __restrict__ nob,
           const float* __restrict__ hw,   const float* __restrict__ hb,
           float* __restrict__ out) {
  __shared__ __align__(16) unsigned char sm[65536];
  const int tid  = threadIdx.x;
  const int lane = tid & 63;
  const int wave = tid >> 6;   // 0..3; owns tokens [64*wave, 64*wave+64)
  const int n16  = lane & 15;
  const int quad = lane >> 4;
  const int qs   = quad & 1;
  const size_t blk_tok = (size_t)blockIdx.x * S;

  float h[D];
  embed_token(x + (blk_tok + tid) * IND, layers[blk_tok + tid],
              fpw, fpb, lemb, fB, h);
  store_h16(sm, tid, h);   // published by barrier 1 (l=0)

  for (int l = 0; l < NL; ++l) {
    // Barrier 1/3: ph1's Q|K/V^T writes scatter into rows whose prior
    // contents other waves read; also publishes embed h (l=0).
    __syncthreads();

    const float* Wi = ipw + l * (3 * D) * D;
    const float* Bi = ipb + l * (3 * D);

    // ---- hoisted weight prep for GEMM2 + fused GEMM3/4 --------------------
    // Issued here so the ~22 dwordx4 global loads overlap ph1+ph2 compute
    // instead of stalling after barrier 3 (latency-bound regime, 2 waves/SIMD).
    // Cost: ~72 VGPRs held across ph2; bounds(256,2) caps at 256 (was 112).
    h4 WoF[4]; f4 bo2[2];
    h4 WaF[8]; f4 ba4[4];
    h4 WbF[8]; f4 bb2[2];
    {
      const float* Wo = opw + l * D * D;
      const float* Bo = opb + l * D;
#pragma unroll
      for (int nt = 0; nt < 2; ++nt) {
        bo2[nt] = *(const f4*)(Bo + nt * 16 + quad * 4);
#pragma unroll
        for (int kh = 0; kh < 2; ++kh)
          WoF[nt * 2 + kh] = bfrag(Wo, nt * 16 + n16, 32, kh, quad);
      }
      const float* Wa = w1 + l * DFF * D;
      const float* Ba = b1 + l * DFF;
#pragma unroll
      for (int ft = 0; ft < 4; ++ft) {
        ba4[ft] = *(const f4*)(Ba + ft * 16 + quad * 4);
#pragma unroll
        for (int kh = 0; kh < 2; ++kh)
          WaF[ft * 2 + kh] = bfrag(Wa, ft * 16 + n16, 32, kh, quad);
      }
      const float* Wb = w2 + l * D * DFF;
      const float* Bb = b2 + l * D;
#pragma unroll
      for (int nt = 0; nt < 2; ++nt) {
        bb2[nt] = *(const f4*)(Bb + nt * 16 + quad * 4);
#pragma unroll
        for (int kh = 0; kh < 4; ++kh)
          WbF[nt * 4 + kh] = bfrag(Wb, nt * 16 + n16, 64, kh, quad);
      }
    }

    // ---- ph1: QKV GEMM; wave owns token tiles wave*4..+4 ------------------
    // Q|K transposed (weights as A-op); bias in C-init; Q pre-scaled by
    // (1/sqrt(dh))*log2(e) so ph2 uses raw v_exp_f32.
    {
      h4 Bf[12]; f4 bqk[4]; float bv[2];
#pragma unroll
      for (int nt = 0; nt < 6; ++nt) {
        const float sc = (nt < 2) ? 0.51006973f : 1.0f;  // 0.35355339*log2(e)
#pragma unroll
        for (int kh = 0; kh < 2; ++kh) {
          f4 wv = *(const f4*)(Wi + (nt * 16 + n16) * D + kh * 16 + quad * 4) * sc;
          uint2 wp{pk2(wv.x, wv.y), pk2(wv.z, wv.w)};
          Bf[nt * 2 + kh] = __builtin_bit_cast(h4, wp);
        }
        if (nt < 4)
          bqk[nt] = *(const f4*)(Bi + nt * 16 + quad * 4) * sc;
        else
          bv[nt - 4] = Bi[nt * 16 + n16];
      }
      h4 Ah[8];
#pragma unroll
      for (int it = 0; it < 4; ++it) {
        const int tok = (wave * 4 + it) * 16 + n16;
        Ah[it * 2]     = afrag32(sm, HOFF, tok, 0, quad);
        Ah[it * 2 + 1] = afrag32(sm, HOFF, tok, 1, quad);
      }
      const int kswz = n16 & 7;  // == tok&7 for tok = tile*16+n16
#pragma unroll
      for (int it = 0; it < 4; ++it) {
        const int tok = (wave * 4 + it) * 16 + n16;
#pragma unroll
        for (int nt = 0; nt < 4; ++nt) {  // Q|K: C^T[feat][tok]
          f4 C = bqk[nt];
          C = MFMA16(Bf[nt * 2], Ah[it * 2], C);
          C = MFMA16(Bf[nt * 2 + 1], Ah[it * 2 + 1], C);
          uint2 p{pk2(C[0], C[1]), pk2(C[2], C[3])};
          *(uint2*)(sm + QKOFF + tok * 128 +
                    (((nt * 2 + (quad >> 1)) ^ kswz) * 16) + (quad & 1) * 8) = p;
        }
#pragma unroll
        for (int nt = 4; nt < 6; ++nt) {  // V token-major -> V^T
          const float bb = bv[nt - 4];
          f4 C = {bb, bb, bb, bb};
          C = MFMA16(Ah[it * 2], Bf[nt * 2], C);
          C = MFMA16(Ah[it * 2 + 1], Bf[nt * 2 + 1], C);
          uint2 p{pk2(C[0], C[1]), pk2(C[2], C[3])};
          const int vf = (nt - 4) * 16 + n16;
          const int tc = (wave * 4 + it) * 4 + quad;  // tok>>2
          *(uint2*)(sm + VOFF + vf * 512 + ((tc ^ ((vf & 7) << 1)) * 8)) = p;
        }
      }
    }
    // Barrier 2/3: Q|K|V visible to all waves for ph2.
    __syncthreads();

    // ---- ph2: flash attention (wave = head) -------------------------------
    // O^T = mfma(V^T, P); V preloaded; A-row 8 = ones so MFMA also produces
    // lsum (row 8 of C). Epilogue: 1 rcp + 1 bpermute + 8B O-store.
    {
      const int hh  = wave;
      const int m   = n16;
      const int msw = m & 7;
      h4 Kf[16], Vf[16];
      const int kbase = QKOFF + (((4 + hh) ^ msw) * 16) + qs * 8;
#pragma unroll
      for (int jt = 0; jt < 16; ++jt) {
        uint2 a = *(const uint2*)(sm + kbase + (jt * 16 + m) * 128);
        if (quad >= 2) { a.x = 0u; a.y = 0u; }   // dh 8->16 zero pad (k dim)
        Kf[jt] = __builtin_bit_cast(h4, a);
      }
      const unsigned fill = (m == 8) ? 0x3C003C00u : 0u;  // row 8 = ones
      const int vbase = VOFF + (hh * 8 + msw) * 512;
      const int vkey  = msw << 1;
#pragma unroll
      for (int jt = 0; jt < 16; ++jt) {
        uint2 a = *(const uint2*)(sm + vbase + (((jt * 4 + quad) ^ vkey) * 8));
        if (m >= 8) { a.x = fill; a.y = fill; }  // rows 9..15 zero, row 8 ones
        Vf[jt] = __builtin_bit_cast(h4, a);
      }
      const int qoff = QKOFF + ((hh ^ msw) * 16) + qs * 8;
      const int ooff = HOFF + (((hh * 2 + quad) ^ msw) * 8);  // quad<2 valid

#pragma unroll 2
      for (int it = 0; it < 16; ++it) {
        const int ti = it * 16 + m;
        h4 Qf = *(const h4*)(sm + qoff + ti * 128);
        f4 Of0 = {0.f, 0.f, 0.f, 0.f}, Of1 = {0.f, 0.f, 0.f, 0.f};
        const f4 Z = {0.f, 0.f, 0.f, 0.f};
#pragma unroll
        for (int jt = 0; jt < 16; ++jt) {
          f4 T = MFMA16(Kf[jt], Qf, Z);
          uint2 pu{pk2(exp2fast(T[0]), exp2fast(T[1])),
                   pk2(exp2fast(T[2]), exp2fast(T[3]))};
          h4 P = __builtin_bit_cast(h4, pu);  // C-frag of T == B-frag of P
          if (jt & 1) Of1 = MFMA16(Vf[jt], P, Of1);
          else        Of0 = MFMA16(Vf[jt], P, Of0);
        }
        f4 Of = Of0 + Of1;
        // C row 8 (quad==2, elem 0) = softmax denominator
        float rinv = __builtin_amdgcn_rcpf(Of[0]);
        rinv = __builtin_bit_cast(
            float, __builtin_amdgcn_ds_bpermute(
                       (32 + m) << 2, __builtin_bit_cast(int, rinv)));
        if (quad < 2) {  // rows 0..7 = O features hh*8+quad*4+r of token ti
          f4 o = Of * rinv;
          uint2 p{pk2(o[0], o[1]), pk2(o[2], o[3])};
          *(uint2*)(sm + ooff + ti * 64) = p;
        }
      }
    }
    // Barrier 3/3: O (cross-head) visible; all K/V reads done.
    __syncthreads();

    // ---- GEMM2: O'^T = Wo x O^T -> VOFF (V dead); own-wave tokens ---------
    {
      const int kswz = n16 & 7;
#pragma unroll
      for (int ii = 0; ii < 4; ++ii) {
        const int tok = (wave * 4 + ii) * 16 + n16;
        h4 A0 = afrag32(sm, HOFF, tok, 0, quad);
        h4 A1 = afrag32(sm, HOFF, tok, 1, quad);
#pragma unroll
        for (int nt = 0; nt < 2; ++nt) {
          f4 C = bo2[nt];
          C = MFMA16(WoF[nt * 2], A0, C);
          C = MFMA16(WoF[nt * 2 + 1], A1, C);
          uint2 p{pk2(C[0], C[1]), pk2(C[2], C[3])};
          *(uint2*)(sm + VOFF + tok * 64 + (((nt * 4 + quad) ^ kswz) * 8)) = p;
        }
      }
    }
    wave_fence();  // O' rows are own-wave

    // ---- token: h += O'; LN1; h' f16 -> HOFF (own rows) -------------------
    add_row32(sm, VOFF, tid, h);
    lnorm(h, ln1g + l * D, ln1b + l * D);
    store_h16(sm, tid, h);
    wave_fence();

    // ---- fused GEMM3+GEMM4 (t stays in registers) -------------------------
    // t^T = gelu(Wa x h'^T); GEMM3's C-frag after gelu IS GEMM4's B-frag at
    // kh=ft (lane n16 = token col, quad*4+e = k within ft block). Verified
    // correct in round 3's passing run.
    {
      const int kswz = n16 & 7;
#pragma unroll
      for (int tt = 0; tt < 4; ++tt) {
        const int tok = (wave * 4 + tt) * 16 + n16;
        h4 A0 = afrag32(sm, HOFF, tok, 0, quad);
        h4 A1 = afrag32(sm, HOFF, tok, 1, quad);
        h4 Pf[4];
#pragma unroll
        for (int ft = 0; ft < 4; ++ft) {
          f4 C = ba4[ft];
          C = MFMA16(WaF[ft * 2], A0, C);
          C = MFMA16(WaF[ft * 2 + 1], A1, C);
          uint2 p{pk2(gelu(C[0]), gelu(C[1])), pk2(gelu(C[2]), gelu(C[3]))};
          Pf[ft] = __builtin_bit_cast(h4, p);
        }
#pragma unroll
        for (int nt = 0; nt < 2; ++nt) {
          f4 C = bb2[nt];
#pragma unroll
          for (int ft = 0; ft < 4; ++ft) C = MFMA16(WbF[nt * 4 + ft], Pf[ft], C);
          uint2 p{pk2(C[0], C[1]), pk2(C[2], C[3])};
          *(uint2*)(sm + VOFF + tok * 64 + (((nt * 4 + quad) ^ kswz) * 8)) = p;
        }
      }
    }
    wave_fence();  // O'' rows are own-wave

    // ---- token: h += O''; LN2; h f16 -> HOFF (next layer's ph1 src) -------
    add_row32(sm, VOFF, tid, h);
    lnorm(h, ln2g + l * D, ln2b + l * D);
    if (l < NL - 1) store_h16(sm, tid, h);  // dead after last layer
  }

  // ---------- final LN + head ----------
  __syncthreads();  // staging overlays HOFF+QKOFF still read by other waves
  lnorm(h, nog, nob);
  float* hs = (float*)sm;  // 25.6 KB staging over dead HOFF+QKOFF
#pragma unroll
  for (int o = 0; o < HOUT; ++o)
    hs[tid * HOUT + o] = dotp<16>(hw + o * D, h) + hb[o];
  __syncthreads();
  f2* og = (f2*)(out + blk_tok * HOUT);
  const f2* os2 = (const f2*)hs;
  for (int i = tid; i < S * HOUT / 2; i += TPB) og[i] = os2[i];
}

extern "C" void kernel_launch(void* const* d_in, const int* in_sizes, int n_in,
                              void* d_out, int out_size, void* d_ws, size_t ws_size,
                              hipStream_t stream) {
  const float* x    = (const float*)d_in[0];
  const int*   lays = (const int*)  d_in[1];
  const float* fpw  = (const float*)d_in[2];
  const float* fpb  = (const float*)d_in[3];
  const float* lemb = (const float*)d_in[4];
  const float* fB   = (const float*)d_in[5];
  const float* ipw  = (const float*)d_in[6];
  const float* ipb  = (const float*)d_in[7];
  const float* opw  = (const float*)d_in[8];
  const float* opb  = (const float*)d_in[9];
  const float* ln1g = (const float*)d_in[10];
  const float* ln1b = (const float*)d_in[11];
  const float* w1   = (const float*)d_in[12];
  const float* b1   = (const float*)d_in[13];
  const float* w2   = (const float*)d_in[14];
  const float* b2   = (const float*)d_in[15];
  const float* ln2g = (const float*)d_in[16];
  const float* ln2b = (const float*)d_in[17];
  const float* nog  = (const float*)d_in[18];
  const float* nob  = (const float*)d_in[19];
  const float* hw   = (const float*)d_in[20];
  const float* hb   = (const float*)d_in[21];
  float* out = (float*)d_out;

  const int nwin = in_sizes[0] / (S * IND);  // 512 windows
  spai_fused<<<nwin, TPB, 0, stream>>>(x, lays, fpw, fpb, lemb, fB, ipw, ipb,
                                       opw, opb, ln1g, ln1b, w1, b1, w2, b2,
                                       ln2g, ln2b, nog, nob, hw, hb, out);
}

// Round 6
// 236.658 us; speedup vs baseline: 1.4316x; 1.0358x over previous
//
#include <hip/hip_runtime.h>

constexpr int S    = 256;
constexpr int D    = 32;
constexpr int NH   = 4;
constexpr int DH   = 8;
constexpr int DFF  = 64;
constexpr int NL   = 4;
constexpr int IND  = 58;
constexpr int HOUT = 25;
constexpr int TPB  = 256;  // 1 window/block, 4 waves; 2 blocks/CU (proven shell)
                           // 512-thread variants SPILL (re-confirmed round 3).
                           // Occupancy is GRID-capped (512 blk x 4 waves / 256
                           // CU = 8 waves/CU): do not chase occupancy.

typedef float  f2 __attribute__((ext_vector_type(2)));
typedef float  f4 __attribute__((ext_vector_type(4)));
typedef __fp16 h2 __attribute__((ext_vector_type(2)));
typedef __fp16 h4 __attribute__((ext_vector_type(4)));
typedef __fp16 h8 __attribute__((ext_vector_type(8)));

__device__ __forceinline__ f4 MFMA16(h4 a, h4 b, f4 c) {
  return __builtin_amdgcn_mfma_f32_16x16x16f16(a, b, c, 0, 0, 0);
}
// CDNA4-native K=32 shape (~2x FLOP-rate of the legacy x16). A/B frags are
// built as cat(K-half0, K-half1); since we build BOTH operands with the same
// slot order, the internal k-slot mapping cancels (layout-safe).
__device__ __forceinline__ f4 MFMA32(h8 a, h8 b, f4 c) {
  return __builtin_amdgcn_mfma_f32_16x16x32_f16(a, b, c, 0, 0, 0);
}
__device__ __forceinline__ h8 hcat(h4 a, h4 b) {
  return __builtin_shufflevector(a, b, 0, 1, 2, 3, 4, 5, 6, 7);
}

// LDS map (bytes), 64 KB. Liveness per layer:
//  HOFF: h f16 (ph1 A-src) -> attn O (ph2 out, GEMM2 src) -> h' f16 (G34 src)
//  QKOFF: Q|K (ph2 in)   [t eliminated: GEMM3->GEMM4 fused in registers]
//  VOFF: V^T (ph2 in) -> O' f16 (LN1 in) -> O'' f16 (LN2 in)
constexpr int HOFF  = 0;      // 16 KB  [256][32] f16, 8B chunks ^(tok&7)
constexpr int QKOFF = 16384;  // 32 KB
constexpr int VOFF  = 49152;  // 16 KB

__device__ __forceinline__ unsigned pk2(float a, float b) {
  h2 h = __builtin_amdgcn_cvt_pkrtz(a, b);
  return __builtin_bit_cast(unsigned, h);
}

__device__ __forceinline__ float exp2fast(float x) {
#if __has_builtin(__builtin_amdgcn_exp2f)
  return __builtin_amdgcn_exp2f(x);   // v_exp_f32 = 2^x, one trans op
#else
  return exp2f(x);
#endif
}

// Compile-time + in-wave-order fence for same-wave LDS RAW.
__device__ __forceinline__ void wave_fence() {
  __builtin_amdgcn_wave_barrier();
  __builtin_amdgcn_sched_barrier(0);
}

// packed-fp32 dot. All register-array loops must FULLY unroll (r3 lesson).
template<int NF2>
__device__ __forceinline__ float dotp(const float* __restrict__ w,
                                      const float* __restrict__ v) {
  const f2* W = (const f2*)w;
  const f2* V = (const f2*)v;
  f2 a0 = {0.f, 0.f}, a1 = {0.f, 0.f};
#pragma unroll
  for (int i = 0; i < NF2; i += 2) a0 += V[i] * W[i];
#pragma unroll
  for (int i = 1; i < NF2; i += 2) a1 += V[i] * W[i];
  f2 s = a0 + a1;
  return s.x + s.y;
}

// tanh-approx GELU via exp2 (log2e folded; verified family r7-r10)
__device__ __forceinline__ float gelu(float x) {
  float u = 2.3022082f * fmaf(0.044715f * x * x, x, x);  // 1.59576912*log2(e)
  return x * __builtin_amdgcn_rcpf(1.0f + exp2fast(-u));
}

// LayerNorm on 32 f32 regs, packed-f32 (v_pk_*) form.
__device__ __forceinline__ void lnorm(float* h, const float* __restrict__ g,
                                      const float* __restrict__ b) {
  f2* hv = (f2*)h;
  f2 s0 = hv[0], s1 = hv[1];
#pragma unroll
  for (int i = 2; i < 16; i += 2) { s0 += hv[i]; s1 += hv[i + 1]; }
  f2 s = s0 + s1;
  const float m = (s.x + s.y) * (1.0f / D);
  const f2 m2 = {m, m};
  f2 v0 = {0.f, 0.f}, v1 = {0.f, 0.f};
#pragma unroll
  for (int i = 0; i < 16; i += 2) {
    f2 c0 = hv[i] - m2;     v0 += c0 * c0;
    f2 c1 = hv[i + 1] - m2; v1 += c1 * c1;
  }
  f2 vs = v0 + v1;
  const float inv = __builtin_amdgcn_rsqf((vs.x + vs.y) * (1.0f / D) + 1e-5f);
  const f2 inv2 = {inv, inv};
  const f2 mi2 = {-m * inv, -m * inv};
  const f2* g2 = (const f2*)g;
  const f2* b2 = (const f2*)b;
#pragma unroll
  for (int i = 0; i < 16; ++i) {
    f2 t = hv[i] * inv2 + mi2;   // (h-m)*inv  as pk_fma
    hv[i] = t * g2[i] + b2[i];   // *g + b     as pk_fma
  }
}

__device__ __forceinline__ void embed_token(
    const float* __restrict__ xrow, int lay,
    const float* __restrict__ fpw, const float* __restrict__ fpb,
    const float* __restrict__ lemb, const float* __restrict__ fB,
    float* __restrict__ h) {
  float xr[IND];
  const f2* xv = (const f2*)xrow;
#pragma unroll
  for (int i = 0; i < 29; ++i) { f2 t = xv[i]; xr[2 * i] = t.x; xr[2 * i + 1] = t.y; }
  const float* le = lemb + lay * D;
  float pe[D];
#pragma unroll
  for (int k = 0; k < 16; ++k) {
    // sin(2*pi*t) = v_sin(fract(t)) in revolutions (verified r9/r10)
    float t = xr[0] * fB[k] + xr[1] * fB[16 + k] + xr[2] * fB[32 + k];
#if __has_builtin(__builtin_amdgcn_sinf) && __has_builtin(__builtin_amdgcn_cosf) && __has_builtin(__builtin_amdgcn_fractf)
    float u = __builtin_amdgcn_fractf(t);
    pe[k]      = __builtin_amdgcn_sinf(u);
    pe[16 + k] = __builtin_amdgcn_cosf(u);
#else
    float sv, cv;
    sincosf(6.2831853071795864f * (t - floorf(t)), &sv, &cv);
    pe[k] = sv; pe[16 + k] = cv;
#endif
  }
#pragma unroll
  for (int d = 0; d < D; ++d)
    h[d] = dotp<29>(fpw + d * IND, xr) + fpb[d] + le[d] + pe[d];
}

// ---- shared fragment helpers (layouts verified r8/r11) ----
// frag from f32 weight row-major [N][K]: lane n16 = row, kh = 16-wide k-half.
__device__ __forceinline__ h4 bfrag(const float* __restrict__ W, int row,
                                    int K, int kh, int quad) {
  f4 w = *(const f4*)(W + row * K + kh * 16 + quad * 4);
  uint2 p{pk2(w.x, w.y), pk2(w.z, w.w)};
  return __builtin_bit_cast(h4, p);
}
// full K=32 weight row as x32 frag (slots 0-3 = kh0, 4-7 = kh1)
__device__ __forceinline__ h8 bfrag8(const float* __restrict__ W, int row,
                                     int quad) {
  return hcat(bfrag(W, row, 32, 0, quad), bfrag(W, row, 32, 1, quad));
}
// token frag from [tok][32] f16, 8B chunks swizzled ^(tok&7)
__device__ __forceinline__ h4 afrag32(const unsigned char* sm, int base,
                                      int tok, int kh, int quad) {
  return *(const h4*)(sm + base + tok * 64 + (((kh * 4 + quad) ^ (tok & 7)) * 8));
}
__device__ __forceinline__ h8 afrag8(const unsigned char* sm, int base,
                                     int tok, int quad) {
  return hcat(afrag32(sm, base, tok, 0, quad), afrag32(sm, base, tok, 1, quad));
}

// Write this thread's h (f32 regs) as swizzled f16 row into HOFF.
__device__ __forceinline__ void store_h16(unsigned char* sm, int tok,
                                          const float* __restrict__ h) {
#pragma unroll
  for (int c = 0; c < 8; ++c) {
    uint2 p{pk2(h[4 * c], h[4 * c + 1]), pk2(h[4 * c + 2], h[4 * c + 3])};
    *(uint2*)(sm + HOFF + tok * 64 + ((c ^ (tok & 7)) * 8)) = p;
  }
}
// Read a swizzled [tok][32] f16 row, accumulate into h (residual add).
__device__ __forceinline__ void add_row32(const unsigned char* sm, int base,
                                          int tok, float* __restrict__ h) {
  f2* hv = (f2*)h;
#pragma unroll
  for (int c = 0; c < 8; ++c) {
    h4 q = *(const h4*)(sm + base + tok * 64 + ((c ^ (tok & 7)) * 8));
    f2 lo = {(float)q[0], (float)q[1]};
    f2 hi = {(float)q[2], (float)q[3]};
    hv[2 * c] += lo;
    hv[2 * c + 1] += hi;
  }
}

// launch_bounds: ONLY (256,2) is spill-free for this family (r5-r10, round 3).
__global__ void __launch_bounds__(TPB, 2)
spai_fused(const float* __restrict__ x,    const int*   __restrict__ layers,
           const float* __restrict__ fpw,  const float* __restrict__ fpb,
           const float* __restrict__ lemb, const float* __restrict__ fB,
           const float* __restrict__ ipw,  const float* __restrict__ ipb,
           const float* __restrict__ opw,  const float* __restrict__ opb,
           const float* __restrict__ ln1g, const float* __restrict__ ln1b,
           const float* __restrict__ w1,   const float* __restrict__ b1,
           const float* __restrict__ w2,   const float* __restrict__ b2,
           const float* __restrict__ ln2g, const float* __restrict__ ln2b,
           const float* __restrict__ nog,  const float* __restrict__ nob,
           const float* __restrict__ hw,   const float* __restrict__ hb,
           float* __restrict__ out) {
  __shared__ __align__(16) unsigned char sm[65536];
  const int tid  = threadIdx.x;
  const int lane = tid & 63;
  const int wave = tid >> 6;   // 0..3; owns tokens [64*wave, 64*wave+64)
  const int n16  = lane & 15;
  const int quad = lane >> 4;
  const int qs   = quad & 1;
  const size_t blk_tok = (size_t)blockIdx.x * S;

  float h[D];
  embed_token(x + (blk_tok + tid) * IND, layers[blk_tok + tid],
              fpw, fpb, lemb, fB, h);
  store_h16(sm, tid, h);   // published by barrier 1 (l=0)

  for (int l = 0; l < NL; ++l) {
    // Barrier 1/3: ph1's Q|K/V^T writes scatter into rows whose prior
    // contents other waves read; also publishes embed h (l=0).
    __syncthreads();

    const float* Wi = ipw + l * (3 * D) * D;
    const float* Bi = ipb + l * (3 * D);

    // ---- ph1: QKV GEMM; wave owns token tiles wave*4..+4 ------------------
    // Q|K transposed (weights as A-op); bias in C-init; Q pre-scaled by
    // (1/sqrt(dh))*log2(e) so ph2 uses raw v_exp_f32. One x32 MFMA per tile.
    {
      h8 Bf[6]; f4 bqk[4]; float bv[2];
#pragma unroll
      for (int nt = 0; nt < 6; ++nt) {
        const float sc = (nt < 2) ? 0.51006973f : 1.0f;  // 0.35355339*log2(e)
        f4 w0 = *(const f4*)(Wi + (nt * 16 + n16) * D + quad * 4) * sc;
        f4 w1 = *(const f4*)(Wi + (nt * 16 + n16) * D + 16 + quad * 4) * sc;
        uint2 p0{pk2(w0.x, w0.y), pk2(w0.z, w0.w)};
        uint2 p1{pk2(w1.x, w1.y), pk2(w1.z, w1.w)};
        Bf[nt] = hcat(__builtin_bit_cast(h4, p0), __builtin_bit_cast(h4, p1));
        if (nt < 4)
          bqk[nt] = *(const f4*)(Bi + nt * 16 + quad * 4) * sc;
        else
          bv[nt - 4] = Bi[nt * 16 + n16];
      }
      h8 Ah[4];
#pragma unroll
      for (int it = 0; it < 4; ++it)
        Ah[it] = afrag8(sm, HOFF, (wave * 4 + it) * 16 + n16, quad);
      const int kswz = n16 & 7;  // == tok&7 for tok = tile*16+n16
#pragma unroll
      for (int it = 0; it < 4; ++it) {
        const int tok = (wave * 4 + it) * 16 + n16;
#pragma unroll
        for (int nt = 0; nt < 4; ++nt) {  // Q|K: C^T[feat][tok]
          f4 C = MFMA32(Bf[nt], Ah[it], bqk[nt]);
          uint2 p{pk2(C[0], C[1]), pk2(C[2], C[3])};
          *(uint2*)(sm + QKOFF + tok * 128 +
                    (((nt * 2 + (quad >> 1)) ^ kswz) * 16) + (quad & 1) * 8) = p;
        }
#pragma unroll
        for (int nt = 4; nt < 6; ++nt) {  // V token-major -> V^T
          const float bb = bv[nt - 4];
          f4 C = MFMA32(Ah[it], Bf[nt], (f4){bb, bb, bb, bb});
          uint2 p{pk2(C[0], C[1]), pk2(C[2], C[3])};
          const int vf = (nt - 4) * 16 + n16;
          const int tc = (wave * 4 + it) * 4 + quad;  // tok>>2
          *(uint2*)(sm + VOFF + vf * 512 + ((tc ^ ((vf & 7) << 1)) * 8)) = p;
        }
      }
    }
    // Barrier 2/3: Q|K|V visible to all waves for ph2.
    __syncthreads();

    // ---- ph2: flash attention (wave = head) -------------------------------
    // QK^T stays x16 (k = dh = 8 padded); PV uses x32 over key-tile pairs.
    // A-row 8 of V = ones so the PV MFMA also produces lsum (row 8 of C).
    {
      const int hh  = wave;
      const int m   = n16;
      const int msw = m & 7;
      h4 Kf[16]; h8 Vf8[8];
      const int kbase = QKOFF + (((4 + hh) ^ msw) * 16) + qs * 8;
#pragma unroll
      for (int jt = 0; jt < 16; ++jt) {
        uint2 a = *(const uint2*)(sm + kbase + (jt * 16 + m) * 128);
        if (quad >= 2) { a.x = 0u; a.y = 0u; }   // dh 8->16 zero pad (k dim)
        Kf[jt] = __builtin_bit_cast(h4, a);
      }
      const unsigned fill = (m == 8) ? 0x3C003C00u : 0u;  // row 8 = ones
      const int vbase = VOFF + (hh * 8 + msw) * 512;
      const int vkey  = msw << 1;
#pragma unroll
      for (int j2 = 0; j2 < 8; ++j2) {   // pair key tiles (2j2, 2j2+1)
        uint2 a = *(const uint2*)(sm + vbase + ((((2 * j2) * 4 + quad) ^ vkey) * 8));
        uint2 b = *(const uint2*)(sm + vbase + ((((2 * j2 + 1) * 4 + quad) ^ vkey) * 8));
        if (m >= 8) { a.x = fill; a.y = fill; b.x = fill; b.y = fill; }
        Vf8[j2] = hcat(__builtin_bit_cast(h4, a), __builtin_bit_cast(h4, b));
      }
      const int qoff = QKOFF + ((hh ^ msw) * 16) + qs * 8;
      const int ooff = HOFF + (((hh * 2 + quad) ^ msw) * 8);  // quad<2 valid

#pragma unroll 2
      for (int it = 0; it < 16; ++it) {
        const int ti = it * 16 + m;
        h4 Qf = *(const h4*)(sm + qoff + ti * 128);
        f4 Of0 = {0.f, 0.f, 0.f, 0.f}, Of1 = {0.f, 0.f, 0.f, 0.f};
        const f4 Z = {0.f, 0.f, 0.f, 0.f};
#pragma unroll
        for (int j2 = 0; j2 < 8; ++j2) {
          f4 T0 = MFMA16(Kf[2 * j2], Qf, Z);
          f4 T1 = MFMA16(Kf[2 * j2 + 1], Qf, Z);
          uint2 pa{pk2(exp2fast(T0[0]), exp2fast(T0[1])),
                   pk2(exp2fast(T0[2]), exp2fast(T0[3]))};
          uint2 pb{pk2(exp2fast(T1[0]), exp2fast(T1[1])),
                   pk2(exp2fast(T1[2]), exp2fast(T1[3]))};
          // P slots must pair with Vf8 slots: 0-3 = tile 2j2, 4-7 = 2j2+1
          h8 P8 = hcat(__builtin_bit_cast(h4, pa), __builtin_bit_cast(h4, pb));
          if (j2 & 1) Of1 = MFMA32(Vf8[j2], P8, Of1);
          else        Of0 = MFMA32(Vf8[j2], P8, Of0);
        }
        f4 Of = Of0 + Of1;
        // C row 8 (quad==2, elem 0) = softmax denominator
        float rinv = __builtin_amdgcn_rcpf(Of[0]);
        rinv = __builtin_bit_cast(
            float, __builtin_amdgcn_ds_bpermute(
                       (32 + m) << 2, __builtin_bit_cast(int, rinv)));
        if (quad < 2) {  // rows 0..7 = O features hh*8+quad*4+r of token ti
          f4 o = Of * rinv;
          uint2 p{pk2(o[0], o[1]), pk2(o[2], o[3])};
          *(uint2*)(sm + ooff + ti * 64) = p;
        }
      }
    }
    // Barrier 3/3: O (cross-head) visible; all K/V reads done.
    __syncthreads();

    // ---- GEMM2: O'^T = Wo x O^T -> VOFF (V dead); own-wave tokens ---------
    {
      const float* Wo = opw + l * D * D;
      const float* Bo = opb + l * D;
      h8 WoF[2]; f4 bo2[2];
#pragma unroll
      for (int nt = 0; nt < 2; ++nt) {
        bo2[nt] = *(const f4*)(Bo + nt * 16 + quad * 4);
        WoF[nt] = bfrag8(Wo, nt * 16 + n16, quad);
      }
      const int kswz = n16 & 7;
#pragma unroll
      for (int ii = 0; ii < 4; ++ii) {
        const int tok = (wave * 4 + ii) * 16 + n16;
        h8 A8 = afrag8(sm, HOFF, tok, quad);
#pragma unroll
        for (int nt = 0; nt < 2; ++nt) {
          f4 C = MFMA32(WoF[nt], A8, bo2[nt]);
          uint2 p{pk2(C[0], C[1]), pk2(C[2], C[3])};
          *(uint2*)(sm + VOFF + tok * 64 + (((nt * 4 + quad) ^ kswz) * 8)) = p;
        }
      }
    }
    wave_fence();  // O' rows are own-wave

    // ---- token: h += O'; LN1; h' f16 -> HOFF (own rows) -------------------
    add_row32(sm, VOFF, tid, h);
    lnorm(h, ln1g + l * D, ln1b + l * D);
    store_h16(sm, tid, h);
    wave_fence();

    // ---- fused GEMM3+GEMM4 (t stays in registers) -------------------------
    // t^T = gelu(Wa x h'^T); GEMM3's C-frag after gelu IS GEMM4's B-frag at
    // kh=ft (verified rounds 3/5). GEMM4 K=64 = two x32 MFMAs over Pf pairs.
    {
      const float* Wa = w1 + l * DFF * D;
      const float* Ba = b1 + l * DFF;
      const float* Wb = w2 + l * D * DFF;
      const float* Bb = b2 + l * D;
      h8 WaF[4]; f4 ba4[4]; h8 WbF[4]; f4 bb2[2];
#pragma unroll
      for (int ft = 0; ft < 4; ++ft) {
        ba4[ft] = *(const f4*)(Ba + ft * 16 + quad * 4);
        WaF[ft] = bfrag8(Wa, ft * 16 + n16, quad);
      }
#pragma unroll
      for (int nt = 0; nt < 2; ++nt) {
        bb2[nt] = *(const f4*)(Bb + nt * 16 + quad * 4);
#pragma unroll
        for (int g = 0; g < 2; ++g)   // k feats 32g..32g+32
          WbF[nt * 2 + g] = hcat(bfrag(Wb, nt * 16 + n16, 64, 2 * g, quad),
                                 bfrag(Wb, nt * 16 + n16, 64, 2 * g + 1, quad));
      }
      const int kswz = n16 & 7;
#pragma unroll
      for (int tt = 0; tt < 4; ++tt) {
        const int tok = (wave * 4 + tt) * 16 + n16;
        h8 A8 = afrag8(sm, HOFF, tok, quad);
        h4 Pf[4];
#pragma unroll
        for (int ft = 0; ft < 4; ++ft) {
          f4 C = MFMA32(WaF[ft], A8, ba4[ft]);
          uint2 p{pk2(gelu(C[0]), gelu(C[1])), pk2(gelu(C[2]), gelu(C[3]))};
          Pf[ft] = __builtin_bit_cast(h4, p);
        }
        h8 P8a = hcat(Pf[0], Pf[1]);  // t-feats 0..32 (matches WbF slot order)
        h8 P8b = hcat(Pf[2], Pf[3]);  // t-feats 32..64
#pragma unroll
        for (int nt = 0; nt < 2; ++nt) {
          f4 C = MFMA32(WbF[nt * 2], P8a, bb2[nt]);
          C = MFMA32(WbF[nt * 2 + 1], P8b, C);
          uint2 p{pk2(C[0], C[1]), pk2(C[2], C[3])};
          *(uint2*)(sm + VOFF + tok * 64 + (((nt * 4 + quad) ^ kswz) * 8)) = p;
        }
      }
    }
    wave_fence();  // O'' rows are own-wave

    // ---- token: h += O''; LN2; h f16 -> HOFF (next layer's ph1 src) -------
    add_row32(sm, VOFF, tid, h);
    lnorm(h, ln2g + l * D, ln2b + l * D);
    if (l < NL - 1) store_h16(sm, tid, h);  // dead after last layer
  }

  // ---------- final LN + head ----------
  __syncthreads();  // staging overlays HOFF+QKOFF still read by other waves
  lnorm(h, nog, nob);
  float* hs = (float*)sm;  // 25.6 KB staging over dead HOFF+QKOFF
#pragma unroll
  for (int o = 0; o < HOUT; ++o)
    hs[tid * HOUT + o] = dotp<16>(hw + o * D, h) + hb[o];
  __syncthreads();
  f2* og = (f2*)(out + blk_tok * HOUT);
  const f2* os2 = (const f2*)hs;
  for (int i = tid; i < S * HOUT / 2; i += TPB) og[i] = os2[i];
}

extern "C" void kernel_launch(void* const* d_in, const int* in_sizes, int n_in,
                              void* d_out, int out_size, void* d_ws, size_t ws_size,
                              hipStream_t stream) {
  const float* x    = (const float*)d_in[0];
  const int*   lays = (const int*)  d_in[1];
  const float* fpw  = (const float*)d_in[2];
  const float* fpb  = (const float*)d_in[3];
  const float* lemb = (const float*)d_in[4];
  const float* fB   = (const float*)d_in[5];
  const float* ipw  = (const float*)d_in[6];
  const float* ipb  = (const float*)d_in[7];
  const float* opw  = (const float*)d_in[8];
  const float* opb  = (const float*)d_in[9];
  const float* ln1g = (const float*)d_in[10];
  const float* ln1b = (const float*)d_in[11];
  const float* w1   = (const float*)d_in[12];
  const float* b1   = (const float*)d_in[13];
  const float* w2   = (const float*)d_in[14];
  const float* b2   = (const float*)d_in[15];
  const float* ln2g = (const float*)d_in[16];
  const float* ln2b = (const float*)d_in[17];
  const float* nog  = (const float*)d_in[18];
  const float* nob  = (const float*)d_in[19];
  const float* hw   = (const float*)d_in[20];
  const float* hb   = (const float*)d_in[21];
  float* out = (float*)d_out;

  const int nwin = in_sizes[0] / (S * IND);  // 512 windows
  spai_fused<<<nwin, TPB, 0, stream>>>(x, lays, fpw, fpb, lemb, fB, ipw, ipb,
                                       opw, opb, ln1g, ln1b, w1, b1, w2, b2,
                                       ln2g, ln2b, nog, nob, hw, hb, out);
}